// Round 1
// baseline (565.696 us; speedup 1.0000x reference)
//
#include <hip/hip_runtime.h>
#include <cmath>

#define NLEV 16
#define HASH_PRIME 2654435761u

struct LvlC {
  float scale[NLEV];
  unsigned stride[NLEV];   // res + 1
  unsigned offset[NLEV];   // cumulative param offset
  unsigned hmask[NLEV];    // size-1 for hash levels (size==2^19), 0 for dense
};

__global__ __launch_bounds__(256) void hgp_kernel(
    const float* __restrict__ pts,
    const float2* __restrict__ txy,
    const float2* __restrict__ txz,
    const float2* __restrict__ tyz,
    float* __restrict__ out,
    LvlC lc, int n)
{
  int i = blockIdx.x * 256 + threadIdx.x;
  if (i >= n) return;

  // GridEncoder.forward input normalization: (x + 1) * 0.5
  float u0 = (pts[3 * i + 0] + 1.0f) * 0.5f;
  float u1 = (pts[3 * i + 1] + 1.0f) * 0.5f;
  float u2 = (pts[3 * i + 2] + 1.0f) * 0.5f;

  float acc[2 * NLEV];
#pragma unroll
  for (int j = 0; j < 2 * NLEV; ++j) acc[j] = 0.0f;

  for (int p = 0; p < 3; ++p) {
    // COO_COMBS = (0,1), (0,2), (1,2)
    const float2* t = (p == 0) ? txy : ((p == 1) ? txz : tyz);
    float a = (p == 2) ? u1 : u0;
    float b = (p == 0) ? u1 : u2;

#pragma unroll
    for (int l = 0; l < NLEV; ++l) {
      float px = a * lc.scale[l] + 0.5f;
      float py = b * lc.scale[l] + 0.5f;
      float fx = floorf(px), fy = floorf(py);
      float rx = px - fx, ry = py - fy;
      unsigned x0 = (unsigned)fx, y0 = (unsigned)fy;
      unsigned x1 = x0 + 1u, y1 = y0 + 1u;

      unsigned i00, i10, i01, i11;
      unsigned hm = lc.hmask[l];
      if (hm) {
        // torch-ngp fast_hash: x ^ (y * prime), uint32 wrap, size is 2^19
        unsigned hy0 = y0 * HASH_PRIME;
        unsigned hy1 = y1 * HASH_PRIME;
        i00 = (x0 ^ hy0) & hm;
        i10 = (x1 ^ hy0) & hm;
        i01 = (x0 ^ hy1) & hm;
        i11 = (x1 ^ hy1) & hm;
      } else {
        unsigned s = lc.stride[l];
        i00 = x0 + y0 * s;   // linear index, always < size -> no mod
        i10 = i00 + 1u;
        i01 = i00 + s;
        i11 = i01 + 1u;
      }
      unsigned o = lc.offset[l];
      float2 f00 = t[o + i00];
      float2 f10 = t[o + i10];
      float2 f01 = t[o + i01];
      float2 f11 = t[o + i11];

      float wx1 = rx, wx0 = 1.0f - rx;
      float wy1 = ry, wy0 = 1.0f - ry;
      float w00 = wx0 * wy0, w10 = wx1 * wy0, w01 = wx0 * wy1, w11 = wx1 * wy1;

      acc[2 * l + 0] += w00 * f00.x + w10 * f10.x + w01 * f01.x + w11 * f11.x;
      acc[2 * l + 1] += w00 * f00.y + w10 * f10.y + w01 * f01.y + w11 * f11.y;
    }
  }

  float4* o4 = (float4*)(out + (size_t)i * (2 * NLEV));
#pragma unroll
  for (int j = 0; j < 8; ++j)
    o4[j] = make_float4(acc[4 * j + 0], acc[4 * j + 1], acc[4 * j + 2], acc[4 * j + 3]);
}

static void compute_levels(LvlC* lc)
{
  // Mirrors the Python _level_constants() with identical double-precision ops:
  // pls = 2.0 ** (log2(2048/16)/15); s = 16 * pls**l - 1; r = ceil(s)+1;
  // p = min(2^19, (r+1)^2) rounded up to 8.
  const double pls = std::pow(2.0, std::log2(2048.0 / 16.0) / 15.0);
  unsigned long long off = 0;
  for (int l = 0; l < NLEV; ++l) {
    double s = 16.0 * std::pow(pls, (double)l) - 1.0;
    lc->scale[l] = (float)s;
    long long r = (long long)std::ceil(s) + 1;
    long long dense = (r + 1) * (r + 1);
    long long sz = dense < (1LL << 19) ? dense : (1LL << 19);
    sz = ((sz + 7) / 8) * 8;
    lc->stride[l] = (unsigned)(r + 1);
    lc->offset[l] = (unsigned)off;
    lc->hmask[l] = (dense > sz) ? (unsigned)(sz - 1) : 0u;  // hash size is 2^19 (pow2)
    off += (unsigned long long)sz;
  }
}

extern "C" void kernel_launch(void* const* d_in, const int* in_sizes, int n_in,
                              void* d_out, int out_size, void* d_ws, size_t ws_size,
                              hipStream_t stream) {
  const float*  pts = (const float*)d_in[0];
  const float2* txy = (const float2*)d_in[1];
  const float2* txz = (const float2*)d_in[2];
  const float2* tyz = (const float2*)d_in[3];
  float* out = (float*)d_out;

  int n = in_sizes[0] / 3;  // 1048576 points

  LvlC lc;
  compute_levels(&lc);

  int block = 256;
  int grid = (n + block - 1) / block;
  hgp_kernel<<<grid, block, 0, stream>>>(pts, txy, txz, tyz, out, lc, n);
}